// Round 8
// baseline (163.759 us; speedup 1.0000x reference)
//
#include <hip/hip_runtime.h>
#include <math.h>

// CliffordDDIDecoder — R8 = R7 (passed, 162.6us) with ONE delta: proj GEMM1
// restructured to be barrier-free. R7 counters showed proj latency/barrier-
// bound (MfmaUtil 7.5%, VALUBusy 24%, HBM 11%, Occ 33% — all idle; 32
// barriers for 128 MFMAs/wave). Now: h tile (32x512, 32KB bf16) staged ONCE
// in fragment-major layout (conflict-free ds_read_b128), one __syncthreads,
// then 16 chunks of {W1 register-double-buffered global loads + 8 MFMA} with
// no barriers. LN/GELU/GEMM2/cliff/prep byte-identical to R7. MFMA readout
// stays BANNED (6/6 failure correlation R2/R3/R5/R6).

#define B_ 16384
#define D_ 512
#define H_ 256
#define R_ 95

typedef __attribute__((ext_vector_type(8))) short short8;   // 8 bf16
typedef __attribute__((ext_vector_type(4))) float f32x4;

#define MFMA(a, b, c) __builtin_amdgcn_mfma_f32_16x16x32_bf16(a, b, c, 0, 0, 0)

__device__ __forceinline__ short f2bf(float x) {            // fp32 -> bf16 RNE
    union { float f; unsigned u; } v; v.f = x;
    unsigned r = v.u + 0x7fffu + ((v.u >> 16) & 1u);
    return (short)(r >> 16);
}
__device__ __forceinline__ float bf2f(short s) {
    union { float f; unsigned u; } v;
    v.u = ((unsigned)(unsigned short)s) << 16;
    return v.f;
}

// exact GELU, erf via Abramowitz-Stegun 7.1.26 (max abs err 1.5e-7 — far
// below the bf16 rounding applied to xs immediately after).
__device__ __forceinline__ float gelu_fast(float x) {
    const float z  = x * 0.70710678118654752f;
    const float az = fabsf(z);
    const float t  = 1.0f / fmaf(0.3275911f, az, 1.0f);
    float p = fmaf(1.061405429f, t, -1.453152027f);
    p = fmaf(p, t, 1.421413741f);
    p = fmaf(p, t, -0.284496736f);
    p = fmaf(p, t, 0.254829592f);
    p *= t;
    const float e  = 1.0f - p * __expf(-az * az);
    const float er = copysignf(e, z);
    return 0.5f * x * (1.0f + er);
}

// ---- prep: W1 -> [16 chunk][256 n][32 k] bf16 ; W2 -> [64 n][256 k] bf16 ----
__global__ __launch_bounds__(256)
void cdd_prep_kernel(const float* __restrict__ Wp1, const float* __restrict__ Wv1,
                     const float* __restrict__ Wp2, const float* __restrict__ Wv2,
                     short* __restrict__ W1c_p, short* __restrict__ W1c_v,
                     short* __restrict__ W2t_p, short* __restrict__ W2t_v)
{
    const int o = blockIdx.x * 256 + threadIdx.x;
    if (o < 16 * 256 * 32) {            // n-fast: coalesced W1 reads
        const int n = o & 255, kin = (o >> 8) & 31, ch = o >> 13;
        const int src = (ch * 32 + kin) * 256 + n;
        const int dst = ch * 8192 + n * 32 + kin;
        W1c_p[dst] = f2bf(Wp1[src]);
        W1c_v[dst] = f2bf(Wv1[src]);
    }
    if (o < 64 * 256) {
        const int n = o >> 8, k = o & 255;
        W2t_p[o] = f2bf(Wp2[k * 64 + n]);
        W2t_v[o] = f2bf(Wv2[k * 64 + n]);
    }
}

// ---- proj: x1=h@W1+b1 -> LN -> exact GELU -> m=x@W2+b2 (bf16 to ws) --------
// grid (512, 2): blockIdx.y picks perp/vuln.
__global__ __launch_bounds__(256, 2)
void cdd_proj_kernel(const float* __restrict__ h_p, const float* __restrict__ h_v,
                     const float* __restrict__ bp1, const float* __restrict__ lgp,
                     const float* __restrict__ lbp, const float* __restrict__ bp2,
                     const float* __restrict__ bv1, const float* __restrict__ lgv,
                     const float* __restrict__ lbv, const float* __restrict__ bv2,
                     const short* __restrict__ W1c_p, const short* __restrict__ W1c_v,
                     const short* __restrict__ W2t_p, const short* __restrict__ W2t_v,
                     short* __restrict__ mp_out, short* __restrict__ mv_out)
{
    // hs fragment-major: block bi=ch*2+mt (ch 0..15, mt 0..1), 64 lanes x 8
    // bf16 contiguous -> K-loop ds_read_b128 lane-consecutive, conflict-free.
    __shared__ __align__(16) short hs[32 * 512];    // 32 KB
    __shared__ __align__(16) short xs[32 * 264];    // gelu(LN(x1)), bf16
    __shared__ __align__(16) float lnbuf[256];      // per-wave LN partials

    const int which = blockIdx.y;
    const float* __restrict__ h   = which ? h_v : h_p;
    const float* __restrict__ b1  = which ? bv1 : bp1;
    const float* __restrict__ lg  = which ? lgv : lgp;
    const float* __restrict__ lb  = which ? lbv : lbp;
    const float* __restrict__ b2  = which ? bv2 : bp2;
    const short* __restrict__ W1c = which ? W1c_v : W1c_p;
    const short* __restrict__ W2t = which ? W2t_v : W2t_p;
    short* __restrict__ mo = which ? mv_out : mp_out;

    const int t = threadIdx.x;
    const int w = t >> 6, l = t & 63, q = l >> 4, c = l & 15;
    const int b0 = blockIdx.x * 32;

    // ---------------- stage full h tile once (fragment-major bf16) ---------
    {
        const int row = t >> 3, kbase = (t & 7) * 64;   // 8 threads/row
        const int mt_s = row >> 4, c_s = row & 15;
        const float* hrp = h + (size_t)(b0 + row) * D_ + kbase;
#pragma unroll
        for (int s = 0; s < 8; ++s) {
            const float4 u0 = *(const float4*)(hrp + s * 8);
            const float4 u1 = *(const float4*)(hrp + s * 8 + 4);
            short8 pk;
            pk[0] = f2bf(u0.x); pk[1] = f2bf(u0.y); pk[2] = f2bf(u0.z); pk[3] = f2bf(u0.w);
            pk[4] = f2bf(u1.x); pk[5] = f2bf(u1.y); pk[6] = f2bf(u1.z); pk[7] = f2bf(u1.w);
            const int k0 = kbase + s * 8;
            const int ch = k0 >> 5, qd = (k0 & 31) >> 3;
            *(short8*)(hs + (ch * 2 + mt_s) * 512 + (qd * 16 + c_s) * 8) = pk;
        }
    }
    __syncthreads();                    // the ONLY barrier before LN

    // ---------------- GEMM1: barrier-free K-loop ---------------------------
    // wave w owns cols [64w,64w+64); W1 register-double-buffered from global.
    f32x4 acc1[2][4];
#pragma unroll
    for (int mt = 0; mt < 2; ++mt)
#pragma unroll
        for (int nt = 0; nt < 4; ++nt) acc1[mt][nt] = 0;

    const short* Wb0 = W1c + (w * 64 + c) * 32 + q * 8;
    short8 wb0[4], wb1[4];
#pragma unroll
    for (int nt = 0; nt < 4; ++nt) wb0[nt] = *(const short8*)(Wb0 + nt * 512);

#pragma unroll 1
    for (int cp = 0; cp < 8; ++cp) {
        const int ch0 = cp * 2, ch1 = cp * 2 + 1;
#pragma unroll
        for (int nt = 0; nt < 4; ++nt)
            wb1[nt] = *(const short8*)(Wb0 + ch1 * 8192 + nt * 512);
        {
            const short8 a0 = *(const short8*)(hs + (ch0 * 2 + 0) * 512 + l * 8);
            const short8 a1 = *(const short8*)(hs + (ch0 * 2 + 1) * 512 + l * 8);
#pragma unroll
            for (int nt = 0; nt < 4; ++nt) {
                acc1[0][nt] = MFMA(a0, wb0[nt], acc1[0][nt]);
                acc1[1][nt] = MFMA(a1, wb0[nt], acc1[1][nt]);
            }
        }
        if (cp < 7) {
#pragma unroll
            for (int nt = 0; nt < 4; ++nt)
                wb0[nt] = *(const short8*)(Wb0 + (ch0 + 2) * 8192 + nt * 512);
        }
        {
            const short8 a0 = *(const short8*)(hs + (ch1 * 2 + 0) * 512 + l * 8);
            const short8 a1 = *(const short8*)(hs + (ch1 * 2 + 1) * 512 + l * 8);
#pragma unroll
            for (int nt = 0; nt < 4; ++nt) {
                acc1[0][nt] = MFMA(a0, wb1[nt], acc1[0][nt]);
                acc1[1][nt] = MFMA(a1, wb1[nt], acc1[1][nt]);
            }
        }
    }

    // ---------------- bias + LayerNorm (fp32 stats) + fast exact GELU ------
    float bb[4], gg[4], ee[4];
#pragma unroll
    for (int nt = 0; nt < 4; ++nt) {
        const int col = w * 64 + nt * 16 + c;
        bb[nt] = b1[col]; gg[nt] = lg[col]; ee[nt] = lb[col];
    }
    float mean[2][4], rstd[2][4];
#pragma unroll
    for (int mt = 0; mt < 2; ++mt)
#pragma unroll
        for (int reg = 0; reg < 4; ++reg) {
            float s1 = 0.f, s2 = 0.f;
#pragma unroll
            for (int nt = 0; nt < 4; ++nt) {
                const float a = acc1[mt][nt][reg] + bb[nt];
                acc1[mt][nt][reg] = a;
                s1 += a; s2 += a * a;
            }
#pragma unroll
            for (int m = 1; m <= 8; m <<= 1) {   // reduce over c (16 lanes)
                s1 += __shfl_xor(s1, m, 64);
                s2 += __shfl_xor(s2, m, 64);
            }
            if (c == 0) {
                const int row = mt * 16 + q * 4 + reg;
                *(float2*)(lnbuf + (w * 32 + row) * 2) = make_float2(s1, s2);
            }
        }
    __syncthreads();
#pragma unroll
    for (int mt = 0; mt < 2; ++mt)
#pragma unroll
        for (int reg = 0; reg < 4; ++reg) {
            const int row = mt * 16 + q * 4 + reg;
            float S1 = 0.f, S2 = 0.f;
#pragma unroll
            for (int w2 = 0; w2 < 4; ++w2) {
                const float2 p = *(const float2*)(lnbuf + (w2 * 32 + row) * 2);
                S1 += p.x; S2 += p.y;
            }
            const float mu = S1 * (1.f / 256.f);
            const float var = S2 * (1.f / 256.f) - mu * mu;
            mean[mt][reg] = mu;
            rstd[mt][reg] = rsqrtf(var + 1e-5f);
        }
#pragma unroll
    for (int mt = 0; mt < 2; ++mt)
#pragma unroll
        for (int reg = 0; reg < 4; ++reg) {
            const int row = mt * 16 + q * 4 + reg;
            const float mu = mean[mt][reg], rs = rstd[mt][reg];
#pragma unroll
            for (int nt = 0; nt < 4; ++nt) {
                const int col = w * 64 + nt * 16 + c;
                const float xv = (acc1[mt][nt][reg] - mu) * rs * gg[nt] + ee[nt];
                xs[row * 264 + col] = f2bf(gelu_fast(xv));
            }
        }
    __syncthreads();

    // ---------------- GEMM2: m(32x64) = xs(32x256) @ W2(256x64) + b2 -------
    f32x4 acc2[2]; acc2[0] = 0; acc2[1] = 0;
    const short* W2b = W2t + (w * 16 + c) * 256 + q * 8;
#pragma unroll
    for (int ks = 0; ks < 8; ++ks) {
        const short8 xa0 = *(const short8*)(xs + c * 264 + ks * 32 + q * 8);
        const short8 xa1 = *(const short8*)(xs + (16 + c) * 264 + ks * 32 + q * 8);
        const short8 wbk = *(const short8*)(W2b + ks * 32);
        acc2[0] = MFMA(xa0, wbk, acc2[0]);
        acc2[1] = MFMA(xa1, wbk, acc2[1]);
    }
    const float bc = b2[w * 16 + c];
#pragma unroll
    for (int mt = 0; mt < 2; ++mt)
#pragma unroll
        for (int reg = 0; reg < 4; ++reg) {
            const int row = mt * 16 + q * 4 + reg;
            mo[(size_t)(b0 + row) * 64 + w * 16 + c] = f2bf(acc2[mt][reg] + bc);
        }
}

// ---- cliff: R7-verbatim — Clifford collapse + VALU-dot readout, T in LDS ---
__global__ __launch_bounds__(256, 2)
void cdd_cliff_kernel(const short* __restrict__ mp, const short* __restrict__ mv,
                      const float* __restrict__ T, const float* __restrict__ gw,
                      float* __restrict__ out)
{
    __shared__ __align__(16) float wfl[32 * 68];    // collapsed w, fp32
    __shared__ __align__(16) float ts[95 * 68];     // T staged (pad 68)
    const int t  = threadIdx.x;
    const int b0 = blockIdx.x * 32;

    // stage T: 95 rows x 16 float4
#pragma unroll
    for (int k = 0; k < 6; ++k) {
        const int o = t + k * 256;
        if (o < 95 * 16) {
            const int rr = o >> 4, c4 = (o & 15) << 2;
            *(float4*)(ts + rr * 68 + c4) = *(const float4*)(T + rr * 64 + c4);
        }
    }

    // collapse: w[row][kq*8 .. +8] from mp,mv (fp32 math, bf16 inputs)
    {
        const int row = t >> 3, kq = t & 7;
        float g[8];
#pragma unroll
        for (int i = 0; i < 8; ++i) g[i] = gw[i];
        const short8 p8 = *(const short8*)(mp + (size_t)(b0 + row) * 64 + kq * 8);
        const short8 q8 = *(const short8*)(mv + (size_t)(b0 + row) * 64 + kq * 8);
        float mpv[8], mvv[8];
#pragma unroll
        for (int i = 0; i < 8; ++i) { mpv[i] = bf2f(p8[i]); mvv[i] = bf2f(q8[i]); }

        constexpr int MSK[8] = {0, 1, 2, 4, 3, 5, 6, 7};
        float v[8];
#pragma unroll
        for (int m = 0; m < 8; ++m) {
            float s = 0.f;
#pragma unroll
            for (int j = 0; j < 8; ++j) {
                const int am = MSK[m], bm = MSK[j];
                const int par = (__popc((am >> 1) & bm) + __popc((am >> 2) & bm)) & 1;
                const float sg = par ? -1.f : 1.f;
                s = fmaf(sg * g[MSK[am ^ bm]], mvv[j], s);
            }
            v[m] = s;
        }
#pragma unroll
        for (int l2 = 0; l2 < 8; ++l2) {
            float s = 0.f;
#pragma unroll
            for (int i = 0; i < 8; ++i) {
                const int am = MSK[i], bm = MSK[l2];
                const int par = (__popc((am >> 1) & bm) + __popc((am >> 2) & bm)) & 1;
                const float sg = par ? -1.f : 1.f;
                s = fmaf(sg * mpv[i], v[MSK[am ^ bm]], s);
            }
            wfl[row * 68 + kq * 8 + l2] = s;
        }
    }
    __syncthreads();

    // readout: thread group-of-8 owns one b-row; w row in registers;
    // ts reads: 8 distinct rows x 8-fold broadcast -> conflict-free.
    {
        const int rr = t >> 3, rl = t & 7;
        float4 wv[16];
#pragma unroll
        for (int cc = 0; cc < 16; ++cc)
            wv[cc] = *(const float4*)(wfl + rr * 68 + cc * 4);
#pragma unroll
        for (int k = 0; k < 12; ++k) {
            const int r = rl + (k << 3);
            if (r < R_) {
                float s = 0.f;
#pragma unroll
                for (int cc = 0; cc < 16; ++cc) {
                    const float4 tv = *(const float4*)(ts + r * 68 + cc * 4);
                    s += wv[cc].x * tv.x + wv[cc].y * tv.y
                       + wv[cc].z * tv.z + wv[cc].w * tv.w;
                }
                out[(size_t)(b0 + rr) * R_ + r] = 0.125f * s;
            }
        }
    }
}

extern "C" void kernel_launch(void* const* d_in, const int* in_sizes, int n_in,
                              void* d_out, int out_size, void* d_ws, size_t ws_size,
                              hipStream_t stream)
{
    const float* h_p = (const float*)d_in[0];
    const float* h_v = (const float*)d_in[1];
    const float* Wp1 = (const float*)d_in[2];
    const float* bp1 = (const float*)d_in[3];
    const float* lgp = (const float*)d_in[4];
    const float* lbp = (const float*)d_in[5];
    const float* Wp2 = (const float*)d_in[6];
    const float* bp2 = (const float*)d_in[7];
    const float* Wv1 = (const float*)d_in[8];
    const float* bv1 = (const float*)d_in[9];
    const float* lgv = (const float*)d_in[10];
    const float* lbv = (const float*)d_in[11];
    const float* Wv2 = (const float*)d_in[12];
    const float* bv2 = (const float*)d_in[13];
    const float* T   = (const float*)d_in[14];
    const float* gw  = (const float*)d_in[15];
    float* out = (float*)d_out;

    // ws layout (4.78 MB), R4/R7-verbatim:
    short* W1c_p = (short*)d_ws;                 // [16][256][32]
    short* W1c_v = W1c_p + 16 * 256 * 32;
    short* W2t_p = W1c_v + 16 * 256 * 32;        // [64][256]
    short* W2t_v = W2t_p + 64 * 256;
    short* mp    = W2t_v + 64 * 256;             // (B,64) bf16
    short* mv    = mp + (size_t)B_ * 64;         // (B,64) bf16

    cdd_prep_kernel<<<512, 256, 0, stream>>>(Wp1, Wv1, Wp2, Wv2,
                                             W1c_p, W1c_v, W2t_p, W2t_v);
    dim3 g1(B_ / 32, 2);
    cdd_proj_kernel<<<g1, 256, 0, stream>>>(h_p, h_v,
                                            bp1, lgp, lbp, bp2,
                                            bv1, lgv, lbv, bv2,
                                            W1c_p, W1c_v, W2t_p, W2t_v,
                                            mp, mv);
    cdd_cliff_kernel<<<B_ / 32, 256, 0, stream>>>(mp, mv, T, gw, out);
}

// Round 9
// 163.461 us; speedup vs baseline: 1.0018x; 1.0018x over previous
//
#include <hip/hip_runtime.h>
#include <math.h>

// CliffordDDIDecoder — R9. R8 post-mortem: proj is latency-bound with an
// occupancy ceiling set by GRID SHAPE (4 blocks/CU x 4 waves = 16 waves max;
// measured 7-10). Barriers were innocent (R8 removed them: 45.6->49.2us,
// occupancy 33->21%). R9 keeps R7's proven barriered K-loop + small LDS but
// runs 8 waves/block (512 thr) on the same 32-row tile: ceiling 32 waves/CU.
// Each wave owns 32 cols (2 n-tiles). GEMM2 on waves 0-3 (R7-verbatim code).
// cliff/prep R7-verbatim. MFMA readout stays BANNED (6/6 failure corr).

#define B_ 16384
#define D_ 512
#define H_ 256
#define R_ 95

typedef __attribute__((ext_vector_type(8))) short short8;   // 8 bf16
typedef __attribute__((ext_vector_type(4))) float f32x4;

#define MFMA(a, b, c) __builtin_amdgcn_mfma_f32_16x16x32_bf16(a, b, c, 0, 0, 0)

__device__ __forceinline__ short f2bf(float x) {            // fp32 -> bf16 RNE
    union { float f; unsigned u; } v; v.f = x;
    unsigned r = v.u + 0x7fffu + ((v.u >> 16) & 1u);
    return (short)(r >> 16);
}
__device__ __forceinline__ float bf2f(short s) {
    union { float f; unsigned u; } v;
    v.u = ((unsigned)(unsigned short)s) << 16;
    return v.f;
}

// exact GELU, erf via Abramowitz-Stegun 7.1.26 (max abs err 1.5e-7)
__device__ __forceinline__ float gelu_fast(float x) {
    const float z  = x * 0.70710678118654752f;
    const float az = fabsf(z);
    const float t  = 1.0f / fmaf(0.3275911f, az, 1.0f);
    float p = fmaf(1.061405429f, t, -1.453152027f);
    p = fmaf(p, t, 1.421413741f);
    p = fmaf(p, t, -0.284496736f);
    p = fmaf(p, t, 0.254829592f);
    p *= t;
    const float e  = 1.0f - p * __expf(-az * az);
    const float er = copysignf(e, z);
    return 0.5f * x * (1.0f + er);
}

// ---- prep: W1 -> [16 chunk][256 n][32 k] bf16 ; W2 -> [64 n][256 k] bf16 ----
__global__ __launch_bounds__(256)
void cdd_prep_kernel(const float* __restrict__ Wp1, const float* __restrict__ Wv1,
                     const float* __restrict__ Wp2, const float* __restrict__ Wv2,
                     short* __restrict__ W1c_p, short* __restrict__ W1c_v,
                     short* __restrict__ W2t_p, short* __restrict__ W2t_v)
{
    const int o = blockIdx.x * 256 + threadIdx.x;
    if (o < 16 * 256 * 32) {            // n-fast: coalesced W1 reads
        const int n = o & 255, kin = (o >> 8) & 31, ch = o >> 13;
        const int src = (ch * 32 + kin) * 256 + n;
        const int dst = ch * 8192 + n * 32 + kin;
        W1c_p[dst] = f2bf(Wp1[src]);
        W1c_v[dst] = f2bf(Wv1[src]);
    }
    if (o < 64 * 256) {
        const int n = o >> 8, k = o & 255;
        W2t_p[o] = f2bf(Wp2[k * 64 + n]);
        W2t_v[o] = f2bf(Wv2[k * 64 + n]);
    }
}

// ---- proj: x1=h@W1+b1 -> LN -> exact GELU -> m=x@W2+b2 (bf16 to ws) --------
// 512 threads = 8 waves; 32-row tile; wave w owns cols [32w, 32w+32).
__global__ __launch_bounds__(512, 4)
void cdd_proj_kernel(const float* __restrict__ h_p, const float* __restrict__ h_v,
                     const float* __restrict__ bp1, const float* __restrict__ lgp,
                     const float* __restrict__ lbp, const float* __restrict__ bp2,
                     const float* __restrict__ bv1, const float* __restrict__ lgv,
                     const float* __restrict__ lbv, const float* __restrict__ bv2,
                     const short* __restrict__ W1c_p, const short* __restrict__ W1c_v,
                     const short* __restrict__ W2t_p, const short* __restrict__ W2t_v,
                     short* __restrict__ mp_out, short* __restrict__ mv_out)
{
    __shared__ __align__(16) short hs[32 * 40];     // h chunk, bf16
    __shared__ __align__(16) short xs[32 * 264];    // gelu(LN(x1)), bf16
    __shared__ __align__(16) float lnbuf[512];      // per-wave LN partials (8 waves)

    const int which = blockIdx.y;
    const float* __restrict__ h   = which ? h_v : h_p;
    const float* __restrict__ b1  = which ? bv1 : bp1;
    const float* __restrict__ lg  = which ? lgv : lgp;
    const float* __restrict__ lb  = which ? lbv : lbp;
    const float* __restrict__ b2  = which ? bv2 : bp2;
    const short* __restrict__ W1c = which ? W1c_v : W1c_p;
    const short* __restrict__ W2t = which ? W2t_v : W2t_p;
    short* __restrict__ mo = which ? mv_out : mp_out;

    const int t = threadIdx.x;
    const int w = t >> 6, l = t & 63, q = l >> 4, c = l & 15;
    const int b0 = blockIdx.x * 32;
    const int hrow = (t & 255) >> 3, hk = (t & 7) * 4;   // stagers: t<256

    // ---------------- GEMM1: acc1[mt][nt] = h(32x512) @ W1(512x256) --------
    // wave w owns cols [32w, 32w+32) -> 2 n-tiles; m-tiles 0..1 (32 rows).
    f32x4 acc1[2][2];
#pragma unroll
    for (int mt = 0; mt < 2; ++mt)
#pragma unroll
        for (int nt = 0; nt < 2; ++nt) acc1[mt][nt] = 0;

    const size_t hoff = (size_t)(b0 + hrow) * D_ + hk;
    const short* Wb0 = W1c + (w * 32 + c) * 32 + q * 8;

    for (int ch = 0; ch < 16; ++ch) {
        // global loads first (issued before barrier; overlap prev MFMA)
        float4 hv;
        if (t < 256) hv = *(const float4*)(h + hoff + ch * 32);
        short8 wb[2];
#pragma unroll
        for (int nt = 0; nt < 2; ++nt)
            wb[nt] = *(const short8*)(Wb0 + ch * 8192 + nt * 512);

        __syncthreads();               // previous chunk's hs readers done
        if (t < 256) {
            union { short s[4]; uint2 u; } pk;
            pk.s[0] = f2bf(hv.x); pk.s[1] = f2bf(hv.y);
            pk.s[2] = f2bf(hv.z); pk.s[3] = f2bf(hv.w);
            *(uint2*)(hs + hrow * 40 + hk) = pk.u;
        }
        __syncthreads();               // hs fully staged

        const short8 a0 = *(const short8*)(hs + c * 40 + q * 8);
        const short8 a1 = *(const short8*)(hs + (16 + c) * 40 + q * 8);
#pragma unroll
        for (int nt = 0; nt < 2; ++nt) {
            acc1[0][nt] = MFMA(a0, wb[nt], acc1[0][nt]);
            acc1[1][nt] = MFMA(a1, wb[nt], acc1[1][nt]);
        }
    }

    // ---------------- bias + LayerNorm (fp32 stats) + fast exact GELU ------
    float bb[2], gg[2], ee[2];
#pragma unroll
    for (int nt = 0; nt < 2; ++nt) {
        const int col = w * 32 + nt * 16 + c;
        bb[nt] = b1[col]; gg[nt] = lg[col]; ee[nt] = lb[col];
    }
#pragma unroll
    for (int mt = 0; mt < 2; ++mt)
#pragma unroll
        for (int reg = 0; reg < 4; ++reg) {
            float s1 = 0.f, s2 = 0.f;
#pragma unroll
            for (int nt = 0; nt < 2; ++nt) {
                const float a = acc1[mt][nt][reg] + bb[nt];
                acc1[mt][nt][reg] = a;
                s1 += a; s2 += a * a;
            }
#pragma unroll
            for (int m = 1; m <= 8; m <<= 1) {   // reduce over c (16 lanes)
                s1 += __shfl_xor(s1, m, 64);
                s2 += __shfl_xor(s2, m, 64);
            }
            if (c == 0) {
                const int row = mt * 16 + q * 4 + reg;
                *(float2*)(lnbuf + (w * 32 + row) * 2) = make_float2(s1, s2);
            }
        }
    __syncthreads();
#pragma unroll
    for (int mt = 0; mt < 2; ++mt)
#pragma unroll
        for (int reg = 0; reg < 4; ++reg) {
            const int row = mt * 16 + q * 4 + reg;
            float S1 = 0.f, S2 = 0.f;
#pragma unroll
            for (int w2 = 0; w2 < 8; ++w2) {
                const float2 p = *(const float2*)(lnbuf + (w2 * 32 + row) * 2);
                S1 += p.x; S2 += p.y;
            }
            const float mu  = S1 * (1.f / 256.f);
            const float var = S2 * (1.f / 256.f) - mu * mu;
            const float rs  = rsqrtf(var + 1e-5f);
#pragma unroll
            for (int nt = 0; nt < 2; ++nt) {
                const int col = w * 32 + nt * 16 + c;
                const float xv = (acc1[mt][nt][reg] - mu) * rs * gg[nt] + ee[nt];
                xs[row * 264 + col] = f2bf(gelu_fast(xv));
            }
        }
    __syncthreads();

    // ---------------- GEMM2: m(32x64) = xs(32x256) @ W2(256x64) + b2 -------
    // waves 0..3 only (R7-verbatim per-wave code); waves 4..7 idle briefly.
    if (w < 4) {
        f32x4 acc2[2]; acc2[0] = 0; acc2[1] = 0;
        const short* W2b = W2t + (w * 16 + c) * 256 + q * 8;
#pragma unroll
        for (int ks = 0; ks < 8; ++ks) {
            const short8 xa0 = *(const short8*)(xs + c * 264 + ks * 32 + q * 8);
            const short8 xa1 = *(const short8*)(xs + (16 + c) * 264 + ks * 32 + q * 8);
            const short8 wbk = *(const short8*)(W2b + ks * 32);
            acc2[0] = MFMA(xa0, wbk, acc2[0]);
            acc2[1] = MFMA(xa1, wbk, acc2[1]);
        }
        const float bc = b2[w * 16 + c];
#pragma unroll
        for (int mt = 0; mt < 2; ++mt)
#pragma unroll
            for (int reg = 0; reg < 4; ++reg) {
                const int row = mt * 16 + q * 4 + reg;
                mo[(size_t)(b0 + row) * 64 + w * 16 + c] = f2bf(acc2[mt][reg] + bc);
            }
    }
}

// ---- cliff: R7-verbatim — Clifford collapse + VALU-dot readout, T in LDS ---
__global__ __launch_bounds__(256, 2)
void cdd_cliff_kernel(const short* __restrict__ mp, const short* __restrict__ mv,
                      const float* __restrict__ T, const float* __restrict__ gw,
                      float* __restrict__ out)
{
    __shared__ __align__(16) float wfl[32 * 68];    // collapsed w, fp32
    __shared__ __align__(16) float ts[95 * 68];     // T staged (pad 68)
    const int t  = threadIdx.x;
    const int b0 = blockIdx.x * 32;

    // stage T: 95 rows x 16 float4
#pragma unroll
    for (int k = 0; k < 6; ++k) {
        const int o = t + k * 256;
        if (o < 95 * 16) {
            const int rr = o >> 4, c4 = (o & 15) << 2;
            *(float4*)(ts + rr * 68 + c4) = *(const float4*)(T + rr * 64 + c4);
        }
    }

    // collapse: w[row][kq*8 .. +8] from mp,mv (fp32 math, bf16 inputs)
    {
        const int row = t >> 3, kq = t & 7;
        float g[8];
#pragma unroll
        for (int i = 0; i < 8; ++i) g[i] = gw[i];
        const short8 p8 = *(const short8*)(mp + (size_t)(b0 + row) * 64 + kq * 8);
        const short8 q8 = *(const short8*)(mv + (size_t)(b0 + row) * 64 + kq * 8);
        float mpv[8], mvv[8];
#pragma unroll
        for (int i = 0; i < 8; ++i) { mpv[i] = bf2f(p8[i]); mvv[i] = bf2f(q8[i]); }

        constexpr int MSK[8] = {0, 1, 2, 4, 3, 5, 6, 7};
        float v[8];
#pragma unroll
        for (int m = 0; m < 8; ++m) {
            float s = 0.f;
#pragma unroll
            for (int j = 0; j < 8; ++j) {
                const int am = MSK[m], bm = MSK[j];
                const int par = (__popc((am >> 1) & bm) + __popc((am >> 2) & bm)) & 1;
                const float sg = par ? -1.f : 1.f;
                s = fmaf(sg * g[MSK[am ^ bm]], mvv[j], s);
            }
            v[m] = s;
        }
#pragma unroll
        for (int l2 = 0; l2 < 8; ++l2) {
            float s = 0.f;
#pragma unroll
            for (int i = 0; i < 8; ++i) {
                const int am = MSK[i], bm = MSK[l2];
                const int par = (__popc((am >> 1) & bm) + __popc((am >> 2) & bm)) & 1;
                const float sg = par ? -1.f : 1.f;
                s = fmaf(sg * mpv[i], v[MSK[am ^ bm]], s);
            }
            wfl[row * 68 + kq * 8 + l2] = s;
        }
    }
    __syncthreads();

    // readout: thread group-of-8 owns one b-row; w row in registers;
    // ts reads: 8 distinct rows x 8-fold broadcast -> conflict-free.
    {
        const int rr = t >> 3, rl = t & 7;
        float4 wv[16];
#pragma unroll
        for (int cc = 0; cc < 16; ++cc)
            wv[cc] = *(const float4*)(wfl + rr * 68 + cc * 4);
#pragma unroll
        for (int k = 0; k < 12; ++k) {
            const int r = rl + (k << 3);
            if (r < R_) {
                float s = 0.f;
#pragma unroll
                for (int cc = 0; cc < 16; ++cc) {
                    const float4 tv = *(const float4*)(ts + r * 68 + cc * 4);
                    s += wv[cc].x * tv.x + wv[cc].y * tv.y
                       + wv[cc].z * tv.z + wv[cc].w * tv.w;
                }
                out[(size_t)(b0 + rr) * R_ + r] = 0.125f * s;
            }
        }
    }
}

extern "C" void kernel_launch(void* const* d_in, const int* in_sizes, int n_in,
                              void* d_out, int out_size, void* d_ws, size_t ws_size,
                              hipStream_t stream)
{
    const float* h_p = (const float*)d_in[0];
    const float* h_v = (const float*)d_in[1];
    const float* Wp1 = (const float*)d_in[2];
    const float* bp1 = (const float*)d_in[3];
    const float* lgp = (const float*)d_in[4];
    const float* lbp = (const float*)d_in[5];
    const float* Wp2 = (const float*)d_in[6];
    const float* bp2 = (const float*)d_in[7];
    const float* Wv1 = (const float*)d_in[8];
    const float* bv1 = (const float*)d_in[9];
    const float* lgv = (const float*)d_in[10];
    const float* lbv = (const float*)d_in[11];
    const float* Wv2 = (const float*)d_in[12];
    const float* bv2 = (const float*)d_in[13];
    const float* T   = (const float*)d_in[14];
    const float* gw  = (const float*)d_in[15];
    float* out = (float*)d_out;

    // ws layout (4.78 MB), R4/R7-verbatim:
    short* W1c_p = (short*)d_ws;                 // [16][256][32]
    short* W1c_v = W1c_p + 16 * 256 * 32;
    short* W2t_p = W1c_v + 16 * 256 * 32;        // [64][256]
    short* W2t_v = W2t_p + 64 * 256;
    short* mp    = W2t_v + 64 * 256;             // (B,64) bf16
    short* mv    = mp + (size_t)B_ * 64;         // (B,64) bf16

    cdd_prep_kernel<<<512, 256, 0, stream>>>(Wp1, Wv1, Wp2, Wv2,
                                             W1c_p, W1c_v, W2t_p, W2t_v);
    dim3 g1(B_ / 32, 2);
    cdd_proj_kernel<<<g1, 512, 0, stream>>>(h_p, h_v,
                                            bp1, lgp, lbp, bp2,
                                            bv1, lgv, lbv, bv2,
                                            W1c_p, W1c_v, W2t_p, W2t_v,
                                            mp, mv);
    cdd_cliff_kernel<<<B_ / 32, 256, 0, stream>>>(mp, mv, T, gw, out);
}

// Round 10
// 158.864 us; speedup vs baseline: 1.0308x; 1.0289x over previous
//
#include <hip/hip_runtime.h>
#include <math.h>

// CliffordDDIDecoder — R10. R7/R8/R9 post-mortems: proj stuck at 45-52us
// regardless of barriers (R8) or occupancy (R9) -> per-wave latency chain:
// only 8 MFMA per 4KB L2 W-batch. R10 doubles m-tiles per wave (64-row block,
// 4 waves x [4 mt x 4 nt] acc): 16 MFMA per W-batch, W L2 traffic halved.
// h staged once per 256-k half in R8's PROVEN fragment-major layout (32KB,
// conflict-free ds_read_b128). Epilogue = R7-proven pattern with mt 2->4.
// cliff/prep R7-verbatim. MFMA readout stays BANNED (6/6 failure corr).

#define B_ 16384
#define D_ 512
#define H_ 256
#define R_ 95

typedef __attribute__((ext_vector_type(8))) short short8;   // 8 bf16
typedef __attribute__((ext_vector_type(4))) float f32x4;

#define MFMA(a, b, c) __builtin_amdgcn_mfma_f32_16x16x32_bf16(a, b, c, 0, 0, 0)

__device__ __forceinline__ short f2bf(float x) {            // fp32 -> bf16 RNE
    union { float f; unsigned u; } v; v.f = x;
    unsigned r = v.u + 0x7fffu + ((v.u >> 16) & 1u);
    return (short)(r >> 16);
}
__device__ __forceinline__ float bf2f(short s) {
    union { float f; unsigned u; } v;
    v.u = ((unsigned)(unsigned short)s) << 16;
    return v.f;
}

// exact GELU, erf via Abramowitz-Stegun 7.1.26 (max abs err 1.5e-7)
__device__ __forceinline__ float gelu_fast(float x) {
    const float z  = x * 0.70710678118654752f;
    const float az = fabsf(z);
    const float t  = 1.0f / fmaf(0.3275911f, az, 1.0f);
    float p = fmaf(1.061405429f, t, -1.453152027f);
    p = fmaf(p, t, 1.421413741f);
    p = fmaf(p, t, -0.284496736f);
    p = fmaf(p, t, 0.254829592f);
    p *= t;
    const float e  = 1.0f - p * __expf(-az * az);
    const float er = copysignf(e, z);
    return 0.5f * x * (1.0f + er);
}

// ---- prep: W1 -> [16 chunk][256 n][32 k] bf16 ; W2 -> [64 n][256 k] bf16 ----
__global__ __launch_bounds__(256)
void cdd_prep_kernel(const float* __restrict__ Wp1, const float* __restrict__ Wv1,
                     const float* __restrict__ Wp2, const float* __restrict__ Wv2,
                     short* __restrict__ W1c_p, short* __restrict__ W1c_v,
                     short* __restrict__ W2t_p, short* __restrict__ W2t_v)
{
    const int o = blockIdx.x * 256 + threadIdx.x;
    if (o < 16 * 256 * 32) {            // n-fast: coalesced W1 reads
        const int n = o & 255, kin = (o >> 8) & 31, ch = o >> 13;
        const int src = (ch * 32 + kin) * 256 + n;
        const int dst = ch * 8192 + n * 32 + kin;
        W1c_p[dst] = f2bf(Wp1[src]);
        W1c_v[dst] = f2bf(Wv1[src]);
    }
    if (o < 64 * 256) {
        const int n = o >> 8, k = o & 255;
        W2t_p[o] = f2bf(Wp2[k * 64 + n]);
        W2t_v[o] = f2bf(Wv2[k * 64 + n]);
    }
}

// ---- proj: x1=h@W1+b1 -> LN -> exact GELU -> m=x@W2+b2 (bf16 to ws) --------
// 64-row blocks, 256 thr (4 waves); wave w owns cols [64w,64w+64), mt 0..3.
// grid (256, 2): blockIdx.y picks perp/vuln.
__global__ __launch_bounds__(256, 2)
void cdd_proj_kernel(const float* __restrict__ h_p, const float* __restrict__ h_v,
                     const float* __restrict__ bp1, const float* __restrict__ lgp,
                     const float* __restrict__ lbp, const float* __restrict__ bp2,
                     const float* __restrict__ bv1, const float* __restrict__ lgv,
                     const float* __restrict__ lbv, const float* __restrict__ bv2,
                     const short* __restrict__ W1c_p, const short* __restrict__ W1c_v,
                     const short* __restrict__ W2t_p, const short* __restrict__ W2t_v,
                     short* __restrict__ mp_out, short* __restrict__ mv_out)
{
    // hs: fragment-major half-strip (64 rows x 256 k), block bi = ch*4+mt:
    // 64 lanes x 8 bf16 contiguous -> ds_read_b128 lane-consecutive.
    __shared__ __align__(16) short hs[64 * 256];    // 32 KB
    __shared__ __align__(16) short xs[64 * 264];    // 33 KB
    __shared__ __align__(16) float lnbuf[512];      // 4 waves x 64 rows x 2

    const int which = blockIdx.y;
    const float* __restrict__ h   = which ? h_v : h_p;
    const float* __restrict__ b1  = which ? bv1 : bp1;
    const float* __restrict__ lg  = which ? lgv : lgp;
    const float* __restrict__ lb  = which ? lbv : lbp;
    const float* __restrict__ b2  = which ? bv2 : bp2;
    const short* __restrict__ W1c = which ? W1c_v : W1c_p;
    const short* __restrict__ W2t = which ? W2t_v : W2t_p;
    short* __restrict__ mo = which ? mv_out : mp_out;

    const int t = threadIdx.x;
    const int w = t >> 6, l = t & 63, q = l >> 4, c = l & 15;
    const int b0 = blockIdx.x * 64;
    // staging map: 4 threads/row, each covers 64 consecutive k of the half
    const int srow = t >> 2, kseg = (t & 3) * 64;
    const int mt_s = srow >> 4, c_s = srow & 15;

    f32x4 acc1[4][4];
#pragma unroll
    for (int mt = 0; mt < 4; ++mt)
#pragma unroll
        for (int nt = 0; nt < 4; ++nt) acc1[mt][nt] = 0;

    const short* Wb0 = W1c + (w * 64 + c) * 32 + q * 8;
    short8 wb0[4], wb1[4];
#pragma unroll
    for (int nt = 0; nt < 4; ++nt) wb0[nt] = *(const short8*)(Wb0 + nt * 512);

    for (int kh = 0; kh < 2; ++kh) {
        // ---- stage this 256-k half (fragment-major bf16) ----
        if (kh) __syncthreads();        // half-0 hs readers done before rewrite
        {
            const float* hrp = h + (size_t)(b0 + srow) * D_ + kh * 256 + kseg;
#pragma unroll
            for (int s = 0; s < 8; ++s) {
                const float4 u0 = *(const float4*)(hrp + s * 8);
                const float4 u1 = *(const float4*)(hrp + s * 8 + 4);
                short8 pk;
                pk[0] = f2bf(u0.x); pk[1] = f2bf(u0.y); pk[2] = f2bf(u0.z); pk[3] = f2bf(u0.w);
                pk[4] = f2bf(u1.x); pk[5] = f2bf(u1.y); pk[6] = f2bf(u1.z); pk[7] = f2bf(u1.w);
                const int kk = kseg + s * 8;
                const int ch = kk >> 5, qd = (kk >> 3) & 3;
                *(short8*)(hs + (ch * 4 + mt_s) * 512 + (qd * 16 + c_s) * 8) = pk;
            }
        }
        __syncthreads();                // hs fully staged

        // ---- compute 8 chunks of this half; W register-double-buffered ----
        for (int ch = 0; ch < 8; ++ch) {
            const int g = kh * 8 + ch;                  // global chunk 0..15
            if (g < 15) {                               // prefetch next W batch
#pragma unroll
                for (int nt = 0; nt < 4; ++nt)
                    wb1[nt] = *(const short8*)(Wb0 + (g + 1) * 8192 + nt * 512);
            }
            short8 a[4];
#pragma unroll
            for (int mt = 0; mt < 4; ++mt)
                a[mt] = *(const short8*)(hs + (ch * 4 + mt) * 512 + l * 8);
#pragma unroll
            for (int mt = 0; mt < 4; ++mt)
#pragma unroll
                for (int nt = 0; nt < 4; ++nt)
                    acc1[mt][nt] = MFMA(a[mt], wb0[nt], acc1[mt][nt]);
#pragma unroll
            for (int nt = 0; nt < 4; ++nt) wb0[nt] = wb1[nt];
        }
    }

    // ---------------- bias + LayerNorm (fp32 stats) + fast exact GELU ------
    float bb[4], gg[4], ee[4];
#pragma unroll
    for (int nt = 0; nt < 4; ++nt) {
        const int col = w * 64 + nt * 16 + c;
        bb[nt] = b1[col]; gg[nt] = lg[col]; ee[nt] = lb[col];
    }
#pragma unroll
    for (int mt = 0; mt < 4; ++mt)
#pragma unroll
        for (int reg = 0; reg < 4; ++reg) {
            float s1 = 0.f, s2 = 0.f;
#pragma unroll
            for (int nt = 0; nt < 4; ++nt) {
                const float a = acc1[mt][nt][reg] + bb[nt];
                acc1[mt][nt][reg] = a;
                s1 += a; s2 += a * a;
            }
#pragma unroll
            for (int m = 1; m <= 8; m <<= 1) {   // reduce over c (16 lanes)
                s1 += __shfl_xor(s1, m, 64);
                s2 += __shfl_xor(s2, m, 64);
            }
            if (c == 0) {
                const int row = mt * 16 + q * 4 + reg;
                *(float2*)(lnbuf + (w * 64 + row) * 2) = make_float2(s1, s2);
            }
        }
    __syncthreads();
#pragma unroll
    for (int mt = 0; mt < 4; ++mt)
#pragma unroll
        for (int reg = 0; reg < 4; ++reg) {
            const int row = mt * 16 + q * 4 + reg;
            float S1 = 0.f, S2 = 0.f;
#pragma unroll
            for (int w2 = 0; w2 < 4; ++w2) {
                const float2 p = *(const float2*)(lnbuf + (w2 * 64 + row) * 2);
                S1 += p.x; S2 += p.y;
            }
            const float mu  = S1 * (1.f / 256.f);
            const float var = S2 * (1.f / 256.f) - mu * mu;
            const float rs  = rsqrtf(var + 1e-5f);
#pragma unroll
            for (int nt = 0; nt < 4; ++nt) {
                const int col = w * 64 + nt * 16 + c;
                const float xv = (acc1[mt][nt][reg] - mu) * rs * gg[nt] + ee[nt];
                xs[row * 264 + col] = f2bf(gelu_fast(xv));
            }
        }
    __syncthreads();

    // ---------------- GEMM2: m(64x64) = xs(64x256) @ W2(256x64) + b2 -------
    // wave w owns n-cols [16w,16w+16); mt 0..3 (R7-proven pattern, mt 2->4).
    f32x4 acc2[4];
#pragma unroll
    for (int mt = 0; mt < 4; ++mt) acc2[mt] = 0;
    const short* W2b = W2t + (w * 16 + c) * 256 + q * 8;
#pragma unroll
    for (int ks = 0; ks < 8; ++ks) {
        const short8 wbk = *(const short8*)(W2b + ks * 32);
#pragma unroll
        for (int mt = 0; mt < 4; ++mt) {
            const short8 xa = *(const short8*)(xs + (mt * 16 + c) * 264 + ks * 32 + q * 8);
            acc2[mt] = MFMA(xa, wbk, acc2[mt]);
        }
    }
    const float bc = b2[w * 16 + c];
#pragma unroll
    for (int mt = 0; mt < 4; ++mt)
#pragma unroll
        for (int reg = 0; reg < 4; ++reg) {
            const int row = mt * 16 + q * 4 + reg;
            mo[(size_t)(b0 + row) * 64 + w * 16 + c] = f2bf(acc2[mt][reg] + bc);
        }
}

// ---- cliff: R7-verbatim — Clifford collapse + VALU-dot readout, T in LDS ---
__global__ __launch_bounds__(256, 2)
void cdd_cliff_kernel(const short* __restrict__ mp, const short* __restrict__ mv,
                      const float* __restrict__ T, const float* __restrict__ gw,
                      float* __restrict__ out)
{
    __shared__ __align__(16) float wfl[32 * 68];    // collapsed w, fp32
    __shared__ __align__(16) float ts[95 * 68];     // T staged (pad 68)
    const int t  = threadIdx.x;
    const int b0 = blockIdx.x * 32;

    // stage T: 95 rows x 16 float4
#pragma unroll
    for (int k = 0; k < 6; ++k) {
        const int o = t + k * 256;
        if (o < 95 * 16) {
            const int rr = o >> 4, c4 = (o & 15) << 2;
            *(float4*)(ts + rr * 68 + c4) = *(const float4*)(T + rr * 64 + c4);
        }
    }

    // collapse: w[row][kq*8 .. +8] from mp,mv (fp32 math, bf16 inputs)
    {
        const int row = t >> 3, kq = t & 7;
        float g[8];
#pragma unroll
        for (int i = 0; i < 8; ++i) g[i] = gw[i];
        const short8 p8 = *(const short8*)(mp + (size_t)(b0 + row) * 64 + kq * 8);
        const short8 q8 = *(const short8*)(mv + (size_t)(b0 + row) * 64 + kq * 8);
        float mpv[8], mvv[8];
#pragma unroll
        for (int i = 0; i < 8; ++i) { mpv[i] = bf2f(p8[i]); mvv[i] = bf2f(q8[i]); }

        constexpr int MSK[8] = {0, 1, 2, 4, 3, 5, 6, 7};
        float v[8];
#pragma unroll
        for (int m = 0; m < 8; ++m) {
            float s = 0.f;
#pragma unroll
            for (int j = 0; j < 8; ++j) {
                const int am = MSK[m], bm = MSK[j];
                const int par = (__popc((am >> 1) & bm) + __popc((am >> 2) & bm)) & 1;
                const float sg = par ? -1.f : 1.f;
                s = fmaf(sg * g[MSK[am ^ bm]], mvv[j], s);
            }
            v[m] = s;
        }
#pragma unroll
        for (int l2 = 0; l2 < 8; ++l2) {
            float s = 0.f;
#pragma unroll
            for (int i = 0; i < 8; ++i) {
                const int am = MSK[i], bm = MSK[l2];
                const int par = (__popc((am >> 1) & bm) + __popc((am >> 2) & bm)) & 1;
                const float sg = par ? -1.f : 1.f;
                s = fmaf(sg * mpv[i], v[MSK[am ^ bm]], s);
            }
            wfl[row * 68 + kq * 8 + l2] = s;
        }
    }
    __syncthreads();

    // readout: thread group-of-8 owns one b-row; w row in registers;
    // ts reads: 8 distinct rows x 8-fold broadcast -> conflict-free.
    {
        const int rr = t >> 3, rl = t & 7;
        float4 wv[16];
#pragma unroll
        for (int cc = 0; cc < 16; ++cc)
            wv[cc] = *(const float4*)(wfl + rr * 68 + cc * 4);
#pragma unroll
        for (int k = 0; k < 12; ++k) {
            const int r = rl + (k << 3);
            if (r < R_) {
                float s = 0.f;
#pragma unroll
                for (int cc = 0; cc < 16; ++cc) {
                    const float4 tv = *(const float4*)(ts + r * 68 + cc * 4);
                    s += wv[cc].x * tv.x + wv[cc].y * tv.y
                       + wv[cc].z * tv.z + wv[cc].w * tv.w;
                }
                out[(size_t)(b0 + rr) * R_ + r] = 0.125f * s;
            }
        }
    }
}

extern "C" void kernel_launch(void* const* d_in, const int* in_sizes, int n_in,
                              void* d_out, int out_size, void* d_ws, size_t ws_size,
                              hipStream_t stream)
{
    const float* h_p = (const float*)d_in[0];
    const float* h_v = (const float*)d_in[1];
    const float* Wp1 = (const float*)d_in[2];
    const float* bp1 = (const float*)d_in[3];
    const float* lgp = (const float*)d_in[4];
    const float* lbp = (const float*)d_in[5];
    const float* Wp2 = (const float*)d_in[6];
    const float* bp2 = (const float*)d_in[7];
    const float* Wv1 = (const float*)d_in[8];
    const float* bv1 = (const float*)d_in[9];
    const float* lgv = (const float*)d_in[10];
    const float* lbv = (const float*)d_in[11];
    const float* Wv2 = (const float*)d_in[12];
    const float* bv2 = (const float*)d_in[13];
    const float* T   = (const float*)d_in[14];
    const float* gw  = (const float*)d_in[15];
    float* out = (float*)d_out;

    // ws layout (4.78 MB), R4/R7-verbatim:
    short* W1c_p = (short*)d_ws;                 // [16][256][32]
    short* W1c_v = W1c_p + 16 * 256 * 32;
    short* W2t_p = W1c_v + 16 * 256 * 32;        // [64][256]
    short* W2t_v = W2t_p + 64 * 256;
    short* mp    = W2t_v + 64 * 256;             // (B,64) bf16
    short* mv    = mp + (size_t)B_ * 64;         // (B,64) bf16

    cdd_prep_kernel<<<512, 256, 0, stream>>>(Wp1, Wv1, Wp2, Wv2,
                                             W1c_p, W1c_v, W2t_p, W2t_v);
    dim3 g1(B_ / 64, 2);
    cdd_proj_kernel<<<g1, 256, 0, stream>>>(h_p, h_v,
                                            bp1, lgp, lbp, bp2,
                                            bv1, lgv, lbv, bv2,
                                            W1c_p, W1c_v, W2t_p, W2t_v,
                                            mp, mv);
    cdd_cliff_kernel<<<B_ / 32, 256, 0, stream>>>(mp, mv, T, gw, out);
}

// Round 11
// 154.755 us; speedup vs baseline: 1.0582x; 1.0266x over previous
//
#include <hip/hip_runtime.h>
#include <math.h>

// CliffordDDIDecoder — R11 = R10 (passed, 158.9us; proj 43.6) + two proj-only
// deltas targeting the serial latency chain (R7-R10 all landed 43-52us;
// VALUBusy math shows ~9K VALU/wave with ~1.4 waves/SIMD -> chain-bound):
//  1) cross-half h prefetch: half-1's 16 float4 loads issue before half-0's
//     compute, hiding their HBM latency under ~2400 cyc of MFMA.
//  2) coalesced staging map: R10's map scattered each wave-load over 64
//     cache lines; new map -> 32 txn/instr, same bytes, same values.
// Numerics bit-identical to R10 (same RNE f2bf, same MFMA order).
// cliff/prep R7/R10-verbatim. MFMA readout stays BANNED (6/6 failure corr).

#define B_ 16384
#define D_ 512
#define H_ 256
#define R_ 95

typedef __attribute__((ext_vector_type(8))) short short8;   // 8 bf16
typedef __attribute__((ext_vector_type(4))) float f32x4;

#define MFMA(a, b, c) __builtin_amdgcn_mfma_f32_16x16x32_bf16(a, b, c, 0, 0, 0)

__device__ __forceinline__ short f2bf(float x) {            // fp32 -> bf16 RNE
    union { float f; unsigned u; } v; v.f = x;
    unsigned r = v.u + 0x7fffu + ((v.u >> 16) & 1u);
    return (short)(r >> 16);
}
__device__ __forceinline__ float bf2f(short s) {
    union { float f; unsigned u; } v;
    v.u = ((unsigned)(unsigned short)s) << 16;
    return v.f;
}

// exact GELU, erf via Abramowitz-Stegun 7.1.26 (max abs err 1.5e-7)
__device__ __forceinline__ float gelu_fast(float x) {
    const float z  = x * 0.70710678118654752f;
    const float az = fabsf(z);
    const float t  = 1.0f / fmaf(0.3275911f, az, 1.0f);
    float p = fmaf(1.061405429f, t, -1.453152027f);
    p = fmaf(p, t, 1.421413741f);
    p = fmaf(p, t, -0.284496736f);
    p = fmaf(p, t, 0.254829592f);
    p *= t;
    const float e  = 1.0f - p * __expf(-az * az);
    const float er = copysignf(e, z);
    return 0.5f * x * (1.0f + er);
}

// ---- prep: W1 -> [16 chunk][256 n][32 k] bf16 ; W2 -> [64 n][256 k] bf16 ----
__global__ __launch_bounds__(256)
void cdd_prep_kernel(const float* __restrict__ Wp1, const float* __restrict__ Wv1,
                     const float* __restrict__ Wp2, const float* __restrict__ Wv2,
                     short* __restrict__ W1c_p, short* __restrict__ W1c_v,
                     short* __restrict__ W2t_p, short* __restrict__ W2t_v)
{
    const int o = blockIdx.x * 256 + threadIdx.x;
    if (o < 16 * 256 * 32) {            // n-fast: coalesced W1 reads
        const int n = o & 255, kin = (o >> 8) & 31, ch = o >> 13;
        const int src = (ch * 32 + kin) * 256 + n;
        const int dst = ch * 8192 + n * 32 + kin;
        W1c_p[dst] = f2bf(Wp1[src]);
        W1c_v[dst] = f2bf(Wv1[src]);
    }
    if (o < 64 * 256) {
        const int n = o >> 8, k = o & 255;
        W2t_p[o] = f2bf(Wp2[k * 64 + n]);
        W2t_v[o] = f2bf(Wv2[k * 64 + n]);
    }
}

// ---- proj: x1=h@W1+b1 -> LN -> exact GELU -> m=x@W2+b2 (bf16 to ws) --------
// 64-row blocks, 256 thr (4 waves); wave w owns cols [64w,64w+64), mt 0..3.
// grid (256, 2): blockIdx.y picks perp/vuln.
__global__ __launch_bounds__(256, 2)
void cdd_proj_kernel(const float* __restrict__ h_p, const float* __restrict__ h_v,
                     const float* __restrict__ bp1, const float* __restrict__ lgp,
                     const float* __restrict__ lbp, const float* __restrict__ bp2,
                     const float* __restrict__ bv1, const float* __restrict__ lgv,
                     const float* __restrict__ lbv, const float* __restrict__ bv2,
                     const short* __restrict__ W1c_p, const short* __restrict__ W1c_v,
                     const short* __restrict__ W2t_p, const short* __restrict__ W2t_v,
                     short* __restrict__ mp_out, short* __restrict__ mv_out)
{
    // hs: fragment-major half-strip (64 rows x 256 k), block bi = ch*4+mt:
    // 64 lanes x 8 bf16 contiguous -> ds_read_b128 lane-consecutive.
    __shared__ __align__(16) short hs[64 * 256];    // 32 KB
    __shared__ __align__(16) short xs[64 * 264];    // 33 KB
    __shared__ __align__(16) float lnbuf[512];      // 4 waves x 64 rows x 2

    const int which = blockIdx.y;
    const float* __restrict__ h   = which ? h_v : h_p;
    const float* __restrict__ b1  = which ? bv1 : bp1;
    const float* __restrict__ lg  = which ? lgv : lgp;
    const float* __restrict__ lb  = which ? lbv : lbp;
    const float* __restrict__ b2  = which ? bv2 : bp2;
    const short* __restrict__ W1c = which ? W1c_v : W1c_p;
    const short* __restrict__ W2t = which ? W2t_v : W2t_p;
    short* __restrict__ mo = which ? mv_out : mp_out;

    const int t = threadIdx.x;
    const int w = t >> 6, l = t & 63, q = l >> 4, c = l & 15;
    const int b0 = blockIdx.x * 64;
    // staging map: 4 threads/row; per s-step, 4 lanes cover one row's 32
    // consecutive k (lanes contiguous across rows -> ~32 txn per wave-load).
    const int srow = t >> 2, kq4 = (t & 3);
    const int mt_s = srow >> 4, c_s = srow & 15;

    f32x4 acc1[4][4];
#pragma unroll
    for (int mt = 0; mt < 4; ++mt)
#pragma unroll
        for (int nt = 0; nt < 4; ++nt) acc1[mt][nt] = 0;

    const short* Wb0 = W1c + (w * 64 + c) * 32 + q * 8;
    short8 wb0[4], wb1[4];
#pragma unroll
    for (int nt = 0; nt < 4; ++nt) wb0[nt] = *(const short8*)(Wb0 + nt * 512);

    // prefetch half-0 h into registers (8 floats/thread/s-step)
    const float* hbase = h + (size_t)(b0 + srow) * D_ + kq4 * 8;
    float4 ha[8], hb[8];
#pragma unroll
    for (int s = 0; s < 8; ++s) {
        ha[s] = *(const float4*)(hbase + s * 32);
        hb[s] = *(const float4*)(hbase + s * 32 + 4);
    }

    for (int kh = 0; kh < 2; ++kh) {
        // ---- stage this 256-k half (fragment-major bf16) from registers ----
        if (kh) __syncthreads();        // half-0 hs readers done before rewrite
#pragma unroll
        for (int s = 0; s < 8; ++s) {
            short8 pk;
            pk[0] = f2bf(ha[s].x); pk[1] = f2bf(ha[s].y);
            pk[2] = f2bf(ha[s].z); pk[3] = f2bf(ha[s].w);
            pk[4] = f2bf(hb[s].x); pk[5] = f2bf(hb[s].y);
            pk[6] = f2bf(hb[s].z); pk[7] = f2bf(hb[s].w);
            // k = s*32 + kq4*8 -> chunk ch = s, quad qd = kq4
            *(short8*)(hs + (s * 4 + mt_s) * 512 + (kq4 * 16 + c_s) * 8) = pk;
        }
        if (kh == 0) {                  // issue half-1 loads NOW: latency
#pragma unroll                          // hides under half-0's 8 chunk-iters
            for (int s = 0; s < 8; ++s) {
                ha[s] = *(const float4*)(hbase + 256 + s * 32);
                hb[s] = *(const float4*)(hbase + 256 + s * 32 + 4);
            }
        }
        __syncthreads();                // hs fully staged

        // ---- compute 8 chunks of this half; W register-double-buffered ----
        for (int ch = 0; ch < 8; ++ch) {
            const int g = kh * 8 + ch;                  // global chunk 0..15
            if (g < 15) {                               // prefetch next W batch
#pragma unroll
                for (int nt = 0; nt < 4; ++nt)
                    wb1[nt] = *(const short8*)(Wb0 + (g + 1) * 8192 + nt * 512);
            }
            short8 a[4];
#pragma unroll
            for (int mt = 0; mt < 4; ++mt)
                a[mt] = *(const short8*)(hs + (ch * 4 + mt) * 512 + l * 8);
#pragma unroll
            for (int mt = 0; mt < 4; ++mt)
#pragma unroll
                for (int nt = 0; nt < 4; ++nt)
                    acc1[mt][nt] = MFMA(a[mt], wb0[nt], acc1[mt][nt]);
#pragma unroll
            for (int nt = 0; nt < 4; ++nt) wb0[nt] = wb1[nt];
        }
    }

    // ---------------- bias + LayerNorm (fp32 stats) + fast exact GELU ------
    float bb[4], gg[4], ee[4];
#pragma unroll
    for (int nt = 0; nt < 4; ++nt) {
        const int col = w * 64 + nt * 16 + c;
        bb[nt] = b1[col]; gg[nt] = lg[col]; ee[nt] = lb[col];
    }
#pragma unroll
    for (int mt = 0; mt < 4; ++mt)
#pragma unroll
        for (int reg = 0; reg < 4; ++reg) {
            float s1 = 0.f, s2 = 0.f;
#pragma unroll
            for (int nt = 0; nt < 4; ++nt) {
                const float a = acc1[mt][nt][reg] + bb[nt];
                acc1[mt][nt][reg] = a;
                s1 += a; s2 += a * a;
            }
#pragma unroll
            for (int m = 1; m <= 8; m <<= 1) {   // reduce over c (16 lanes)
                s1 += __shfl_xor(s1, m, 64);
                s2 += __shfl_xor(s2, m, 64);
            }
            if (c == 0) {
                const int row = mt * 16 + q * 4 + reg;
                *(float2*)(lnbuf + (w * 64 + row) * 2) = make_float2(s1, s2);
            }
        }
    __syncthreads();
#pragma unroll
    for (int mt = 0; mt < 4; ++mt)
#pragma unroll
        for (int reg = 0; reg < 4; ++reg) {
            const int row = mt * 16 + q * 4 + reg;
            float S1 = 0.f, S2 = 0.f;
#pragma unroll
            for (int w2 = 0; w2 < 4; ++w2) {
                const float2 p = *(const float2*)(lnbuf + (w2 * 64 + row) * 2);
                S1 += p.x; S2 += p.y;
            }
            const float mu  = S1 * (1.f / 256.f);
            const float var = S2 * (1.f / 256.f) - mu * mu;
            const float rs  = rsqrtf(var + 1e-5f);
#pragma unroll
            for (int nt = 0; nt < 4; ++nt) {
                const int col = w * 64 + nt * 16 + c;
                const float xv = (acc1[mt][nt][reg] - mu) * rs * gg[nt] + ee[nt];
                xs[row * 264 + col] = f2bf(gelu_fast(xv));
            }
        }
    __syncthreads();

    // ---------------- GEMM2: m(64x64) = xs(64x256) @ W2(256x64) + b2 -------
    // wave w owns n-cols [16w,16w+16); mt 0..3 (R7-proven pattern, mt 2->4).
    f32x4 acc2[4];
#pragma unroll
    for (int mt = 0; mt < 4; ++mt) acc2[mt] = 0;
    const short* W2b = W2t + (w * 16 + c) * 256 + q * 8;
#pragma unroll
    for (int ks = 0; ks < 8; ++ks) {
        const short8 wbk = *(const short8*)(W2b + ks * 32);
#pragma unroll
        for (int mt = 0; mt < 4; ++mt) {
            const short8 xa = *(const short8*)(xs + (mt * 16 + c) * 264 + ks * 32 + q * 8);
            acc2[mt] = MFMA(xa, wbk, acc2[mt]);
        }
    }
    const float bc = b2[w * 16 + c];
#pragma unroll
    for (int mt = 0; mt < 4; ++mt)
#pragma unroll
        for (int reg = 0; reg < 4; ++reg) {
            const int row = mt * 16 + q * 4 + reg;
            mo[(size_t)(b0 + row) * 64 + w * 16 + c] = f2bf(acc2[mt][reg] + bc);
        }
}

// ---- cliff: R7-verbatim — Clifford collapse + VALU-dot readout, T in LDS ---
__global__ __launch_bounds__(256, 2)
void cdd_cliff_kernel(const short* __restrict__ mp, const short* __restrict__ mv,
                      const float* __restrict__ T, const float* __restrict__ gw,
                      float* __restrict__ out)
{
    __shared__ __align__(16) float wfl[32 * 68];    // collapsed w, fp32
    __shared__ __align__(16) float ts[95 * 68];     // T staged (pad 68)
    const int t  = threadIdx.x;
    const int b0 = blockIdx.x * 32;

    // stage T: 95 rows x 16 float4
#pragma unroll
    for (int k = 0; k < 6; ++k) {
        const int o = t + k * 256;
        if (o < 95 * 16) {
            const int rr = o >> 4, c4 = (o & 15) << 2;
            *(float4*)(ts + rr * 68 + c4) = *(const float4*)(T + rr * 64 + c4);
        }
    }

    // collapse: w[row][kq*8 .. +8] from mp,mv (fp32 math, bf16 inputs)
    {
        const int row = t >> 3, kq = t & 7;
        float g[8];
#pragma unroll
        for (int i = 0; i < 8; ++i) g[i] = gw[i];
        const short8 p8 = *(const short8*)(mp + (size_t)(b0 + row) * 64 + kq * 8);
        const short8 q8 = *(const short8*)(mv + (size_t)(b0 + row) * 64 + kq * 8);
        float mpv[8], mvv[8];
#pragma unroll
        for (int i = 0; i < 8; ++i) { mpv[i] = bf2f(p8[i]); mvv[i] = bf2f(q8[i]); }

        constexpr int MSK[8] = {0, 1, 2, 4, 3, 5, 6, 7};
        float v[8];
#pragma unroll
        for (int m = 0; m < 8; ++m) {
            float s = 0.f;
#pragma unroll
            for (int j = 0; j < 8; ++j) {
                const int am = MSK[m], bm = MSK[j];
                const int par = (__popc((am >> 1) & bm) + __popc((am >> 2) & bm)) & 1;
                const float sg = par ? -1.f : 1.f;
                s = fmaf(sg * g[MSK[am ^ bm]], mvv[j], s);
            }
            v[m] = s;
        }
#pragma unroll
        for (int l2 = 0; l2 < 8; ++l2) {
            float s = 0.f;
#pragma unroll
            for (int i = 0; i < 8; ++i) {
                const int am = MSK[i], bm = MSK[l2];
                const int par = (__popc((am >> 1) & bm) + __popc((am >> 2) & bm)) & 1;
                const float sg = par ? -1.f : 1.f;
                s = fmaf(sg * mpv[i], v[MSK[am ^ bm]], s);
            }
            wfl[row * 68 + kq * 8 + l2] = s;
        }
    }
    __syncthreads();

    // readout: thread group-of-8 owns one b-row; w row in registers;
    // ts reads: 8 distinct rows x 8-fold broadcast -> conflict-free.
    {
        const int rr = t >> 3, rl = t & 7;
        float4 wv[16];
#pragma unroll
        for (int cc = 0; cc < 16; ++cc)
            wv[cc] = *(const float4*)(wfl + rr * 68 + cc * 4);
#pragma unroll
        for (int k = 0; k < 12; ++k) {
            const int r = rl + (k << 3);
            if (r < R_) {
                float s = 0.f;
#pragma unroll
                for (int cc = 0; cc < 16; ++cc) {
                    const float4 tv = *(const float4*)(ts + r * 68 + cc * 4);
                    s += wv[cc].x * tv.x + wv[cc].y * tv.y
                       + wv[cc].z * tv.z + wv[cc].w * tv.w;
                }
                out[(size_t)(b0 + rr) * R_ + r] = 0.125f * s;
            }
        }
    }
}

extern "C" void kernel_launch(void* const* d_in, const int* in_sizes, int n_in,
                              void* d_out, int out_size, void* d_ws, size_t ws_size,
                              hipStream_t stream)
{
    const float* h_p = (const float*)d_in[0];
    const float* h_v = (const float*)d_in[1];
    const float* Wp1 = (const float*)d_in[2];
    const float* bp1 = (const float*)d_in[3];
    const float* lgp = (const float*)d_in[4];
    const float* lbp = (const float*)d_in[5];
    const float* Wp2 = (const float*)d_in[6];
    const float* bp2 = (const float*)d_in[7];
    const float* Wv1 = (const float*)d_in[8];
    const float* bv1 = (const float*)d_in[9];
    const float* lgv = (const float*)d_in[10];
    const float* lbv = (const float*)d_in[11];
    const float* Wv2 = (const float*)d_in[12];
    const float* bv2 = (const float*)d_in[13];
    const float* T   = (const float*)d_in[14];
    const float* gw  = (const float*)d_in[15];
    float* out = (float*)d_out;

    // ws layout (4.78 MB), R4/R7-verbatim:
    short* W1c_p = (short*)d_ws;                 // [16][256][32]
    short* W1c_v = W1c_p + 16 * 256 * 32;
    short* W2t_p = W1c_v + 16 * 256 * 32;        // [64][256]
    short* W2t_v = W2t_p + 64 * 256;
    short* mp    = W2t_v + 64 * 256;             // (B,64) bf16
    short* mv    = mp + (size_t)B_ * 64;         // (B,64) bf16

    cdd_prep_kernel<<<512, 256, 0, stream>>>(Wp1, Wv1, Wp2, Wv2,
                                             W1c_p, W1c_v, W2t_p, W2t_v);
    dim3 g1(B_ / 64, 2);
    cdd_proj_kernel<<<g1, 256, 0, stream>>>(h_p, h_v,
                                            bp1, lgp, lbp, bp2,
                                            bv1, lgv, lbv, bv2,
                                            W1c_p, W1c_v, W2t_p, W2t_v,
                                            mp, mv);
    cdd_cliff_kernel<<<B_ / 32, 256, 0, stream>>>(mp, mv, T, gw, out);
}

// Round 12
// 152.335 us; speedup vs baseline: 1.0750x; 1.0159x over previous
//
#include <hip/hip_runtime.h>
#include <math.h>

// CliffordDDIDecoder — R12 = R11 (passed, 154.75us timed) + ONE delta:
// proj LDS 68.6 -> 51 KB (h staged in 128-k quarters, hs 16 KB) to raise the
// blocks/CU ceiling 2 -> 3 (LDS was the binding occupancy limit: 160/68.6=2).
// Staging map is R11's coalesced 4-thr/row map re-indexed per quarter —
// values bit-identical, MFMA order unchanged. R11 profile anomaly (all
// metrics uniformly /1.79, counters identical) attributed to clock state;
// timed graph is ground truth. cliff/prep R7-verbatim. MFMA readout BANNED.

#define B_ 16384
#define D_ 512
#define H_ 256
#define R_ 95

typedef __attribute__((ext_vector_type(8))) short short8;   // 8 bf16
typedef __attribute__((ext_vector_type(4))) float f32x4;

#define MFMA(a, b, c) __builtin_amdgcn_mfma_f32_16x16x32_bf16(a, b, c, 0, 0, 0)

__device__ __forceinline__ short f2bf(float x) {            // fp32 -> bf16 RNE
    union { float f; unsigned u; } v; v.f = x;
    unsigned r = v.u + 0x7fffu + ((v.u >> 16) & 1u);
    return (short)(r >> 16);
}
__device__ __forceinline__ float bf2f(short s) {
    union { float f; unsigned u; } v;
    v.u = ((unsigned)(unsigned short)s) << 16;
    return v.f;
}

// exact GELU, erf via Abramowitz-Stegun 7.1.26 (max abs err 1.5e-7)
__device__ __forceinline__ float gelu_fast(float x) {
    const float z  = x * 0.70710678118654752f;
    const float az = fabsf(z);
    const float t  = 1.0f / fmaf(0.3275911f, az, 1.0f);
    float p = fmaf(1.061405429f, t, -1.453152027f);
    p = fmaf(p, t, 1.421413741f);
    p = fmaf(p, t, -0.284496736f);
    p = fmaf(p, t, 0.254829592f);
    p *= t;
    const float e  = 1.0f - p * __expf(-az * az);
    const float er = copysignf(e, z);
    return 0.5f * x * (1.0f + er);
}

// ---- prep: W1 -> [16 chunk][256 n][32 k] bf16 ; W2 -> [64 n][256 k] bf16 ----
__global__ __launch_bounds__(256)
void cdd_prep_kernel(const float* __restrict__ Wp1, const float* __restrict__ Wv1,
                     const float* __restrict__ Wp2, const float* __restrict__ Wv2,
                     short* __restrict__ W1c_p, short* __restrict__ W1c_v,
                     short* __restrict__ W2t_p, short* __restrict__ W2t_v)
{
    const int o = blockIdx.x * 256 + threadIdx.x;
    if (o < 16 * 256 * 32) {            // n-fast: coalesced W1 reads
        const int n = o & 255, kin = (o >> 8) & 31, ch = o >> 13;
        const int src = (ch * 32 + kin) * 256 + n;
        const int dst = ch * 8192 + n * 32 + kin;
        W1c_p[dst] = f2bf(Wp1[src]);
        W1c_v[dst] = f2bf(Wv1[src]);
    }
    if (o < 64 * 256) {
        const int n = o >> 8, k = o & 255;
        W2t_p[o] = f2bf(Wp2[k * 64 + n]);
        W2t_v[o] = f2bf(Wv2[k * 64 + n]);
    }
}

// ---- proj: x1=h@W1+b1 -> LN -> exact GELU -> m=x@W2+b2 (bf16 to ws) --------
// 64-row blocks, 256 thr (4 waves); wave w owns cols [64w,64w+64), mt 0..3.
// h staged in 128-k quarters (hs 16 KB); LDS total 51 KB -> 3 blocks/CU.
__global__ __launch_bounds__(256, 2)
void cdd_proj_kernel(const float* __restrict__ h_p, const float* __restrict__ h_v,
                     const float* __restrict__ bp1, const float* __restrict__ lgp,
                     const float* __restrict__ lbp, const float* __restrict__ bp2,
                     const float* __restrict__ bv1, const float* __restrict__ lgv,
                     const float* __restrict__ lbv, const float* __restrict__ bv2,
                     const short* __restrict__ W1c_p, const short* __restrict__ W1c_v,
                     const short* __restrict__ W2t_p, const short* __restrict__ W2t_v,
                     short* __restrict__ mp_out, short* __restrict__ mv_out)
{
    // hs: fragment-major quarter-strip (64 rows x 128 k), block bi = chl*4+mt:
    // 64 lanes x 8 bf16 contiguous -> ds_read_b128 lane-consecutive.
    __shared__ __align__(16) short hs[16 * 512];    // 16 KB
    __shared__ __align__(16) short xs[64 * 264];    // 33 KB
    __shared__ __align__(16) float lnbuf[512];      // 4 waves x 64 rows x 2

    const int which = blockIdx.y;
    const float* __restrict__ h   = which ? h_v : h_p;
    const float* __restrict__ b1  = which ? bv1 : bp1;
    const float* __restrict__ lg  = which ? lgv : lgp;
    const float* __restrict__ lb  = which ? lbv : lbp;
    const float* __restrict__ b2  = which ? bv2 : bp2;
    const short* __restrict__ W1c = which ? W1c_v : W1c_p;
    const short* __restrict__ W2t = which ? W2t_v : W2t_p;
    short* __restrict__ mo = which ? mv_out : mp_out;

    const int t = threadIdx.x;
    const int w = t >> 6, l = t & 63, q = l >> 4, c = l & 15;
    const int b0 = blockIdx.x * 64;
    // staging map: 4 threads/row; per s-step the 4 lanes of a row cover 32
    // consecutive k (2 cache lines/row, ~32 txn per wave-load).
    const int srow = t >> 2, kq4 = (t & 3);
    const int mt_s = srow >> 4, c_s = srow & 15;

    f32x4 acc1[4][4];
#pragma unroll
    for (int mt = 0; mt < 4; ++mt)
#pragma unroll
        for (int nt = 0; nt < 4; ++nt) acc1[mt][nt] = 0;

    const short* Wb0 = W1c + (w * 64 + c) * 32 + q * 8;
    short8 wb0[4], wb1[4];
#pragma unroll
    for (int nt = 0; nt < 4; ++nt) wb0[nt] = *(const short8*)(Wb0 + nt * 512);

    // prefetch quarter-0 h into registers (4 s-steps x 8 floats)
    const float* hbase = h + (size_t)(b0 + srow) * D_ + kq4 * 8;
    float4 ha[4], hb[4];
#pragma unroll
    for (int s = 0; s < 4; ++s) {
        ha[s] = *(const float4*)(hbase + s * 32);
        hb[s] = *(const float4*)(hbase + s * 32 + 4);
    }

    for (int qh = 0; qh < 4; ++qh) {
        // ---- stage this 128-k quarter (fragment-major bf16) from regs ----
        if (qh) __syncthreads();        // previous quarter's hs readers done
#pragma unroll
        for (int s = 0; s < 4; ++s) {
            short8 pk;
            pk[0] = f2bf(ha[s].x); pk[1] = f2bf(ha[s].y);
            pk[2] = f2bf(ha[s].z); pk[3] = f2bf(ha[s].w);
            pk[4] = f2bf(hb[s].x); pk[5] = f2bf(hb[s].y);
            pk[6] = f2bf(hb[s].z); pk[7] = f2bf(hb[s].w);
            // local k = s*32 + kq4*8 -> chunk chl = s, quad = kq4
            *(short8*)(hs + (s * 4 + mt_s) * 512 + (kq4 * 16 + c_s) * 8) = pk;
        }
        if (qh < 3) {                   // issue next quarter's loads NOW
#pragma unroll
            for (int s = 0; s < 4; ++s) {
                ha[s] = *(const float4*)(hbase + (qh + 1) * 128 + s * 32);
                hb[s] = *(const float4*)(hbase + (qh + 1) * 128 + s * 32 + 4);
            }
        }
        __syncthreads();                // hs fully staged

        // ---- compute 4 chunks of this quarter; W register-dbuffered ----
        for (int chl = 0; chl < 4; ++chl) {
            const int g = qh * 4 + chl;                 // global chunk 0..15
            if (g < 15) {                               // prefetch next W batch
#pragma unroll
                for (int nt = 0; nt < 4; ++nt)
                    wb1[nt] = *(const short8*)(Wb0 + (g + 1) * 8192 + nt * 512);
            }
            short8 a[4];
#pragma unroll
            for (int mt = 0; mt < 4; ++mt)
                a[mt] = *(const short8*)(hs + (chl * 4 + mt) * 512 + l * 8);
#pragma unroll
            for (int mt = 0; mt < 4; ++mt)
#pragma unroll
                for (int nt = 0; nt < 4; ++nt)
                    acc1[mt][nt] = MFMA(a[mt], wb0[nt], acc1[mt][nt]);
#pragma unroll
            for (int nt = 0; nt < 4; ++nt) wb0[nt] = wb1[nt];
        }
    }

    // ---------------- bias + LayerNorm (fp32 stats) + fast exact GELU ------
    float bb[4], gg[4], ee[4];
#pragma unroll
    for (int nt = 0; nt < 4; ++nt) {
        const int col = w * 64 + nt * 16 + c;
        bb[nt] = b1[col]; gg[nt] = lg[col]; ee[nt] = lb[col];
    }
#pragma unroll
    for (int mt = 0; mt < 4; ++mt)
#pragma unroll
        for (int reg = 0; reg < 4; ++reg) {
            float s1 = 0.f, s2 = 0.f;
#pragma unroll
            for (int nt = 0; nt < 4; ++nt) {
                const float a = acc1[mt][nt][reg] + bb[nt];
                acc1[mt][nt][reg] = a;
                s1 += a; s2 += a * a;
            }
#pragma unroll
            for (int m = 1; m <= 8; m <<= 1) {   // reduce over c (16 lanes)
                s1 += __shfl_xor(s1, m, 64);
                s2 += __shfl_xor(s2, m, 64);
            }
            if (c == 0) {
                const int row = mt * 16 + q * 4 + reg;
                *(float2*)(lnbuf + (w * 64 + row) * 2) = make_float2(s1, s2);
            }
        }
    __syncthreads();
#pragma unroll
    for (int mt = 0; mt < 4; ++mt)
#pragma unroll
        for (int reg = 0; reg < 4; ++reg) {
            const int row = mt * 16 + q * 4 + reg;
            float S1 = 0.f, S2 = 0.f;
#pragma unroll
            for (int w2 = 0; w2 < 4; ++w2) {
                const float2 p = *(const float2*)(lnbuf + (w2 * 64 + row) * 2);
                S1 += p.x; S2 += p.y;
            }
            const float mu  = S1 * (1.f / 256.f);
            const float var = S2 * (1.f / 256.f) - mu * mu;
            const float rs  = rsqrtf(var + 1e-5f);
#pragma unroll
            for (int nt = 0; nt < 4; ++nt) {
                const int col = w * 64 + nt * 16 + c;
                const float xv = (acc1[mt][nt][reg] - mu) * rs * gg[nt] + ee[nt];
                xs[row * 264 + col] = f2bf(gelu_fast(xv));
            }
        }
    __syncthreads();

    // ---------------- GEMM2: m(64x64) = xs(64x256) @ W2(256x64) + b2 -------
    // wave w owns n-cols [16w,16w+16); mt 0..3 (R7-proven pattern, mt 2->4).
    f32x4 acc2[4];
#pragma unroll
    for (int mt = 0; mt < 4; ++mt) acc2[mt] = 0;
    const short* W2b = W2t + (w * 16 + c) * 256 + q * 8;
#pragma unroll
    for (int ks = 0; ks < 8; ++ks) {
        const short8 wbk = *(const short8*)(W2b + ks * 32);
#pragma unroll
        for (int mt = 0; mt < 4; ++mt) {
            const short8 xa = *(const short8*)(xs + (mt * 16 + c) * 264 + ks * 32 + q * 8);
            acc2[mt] = MFMA(xa, wbk, acc2[mt]);
        }
    }
    const float bc = b2[w * 16 + c];
#pragma unroll
    for (int mt = 0; mt < 4; ++mt)
#pragma unroll
        for (int reg = 0; reg < 4; ++reg) {
            const int row = mt * 16 + q * 4 + reg;
            mo[(size_t)(b0 + row) * 64 + w * 16 + c] = f2bf(acc2[mt][reg] + bc);
        }
}

// ---- cliff: R7-verbatim — Clifford collapse + VALU-dot readout, T in LDS ---
__global__ __launch_bounds__(256, 2)
void cdd_cliff_kernel(const short* __restrict__ mp, const short* __restrict__ mv,
                      const float* __restrict__ T, const float* __restrict__ gw,
                      float* __restrict__ out)
{
    __shared__ __align__(16) float wfl[32 * 68];    // collapsed w, fp32
    __shared__ __align__(16) float ts[95 * 68];     // T staged (pad 68)
    const int t  = threadIdx.x;
    const int b0 = blockIdx.x * 32;

    // stage T: 95 rows x 16 float4
#pragma unroll
    for (int k = 0; k < 6; ++k) {
        const int o = t + k * 256;
        if (o < 95 * 16) {
            const int rr = o >> 4, c4 = (o & 15) << 2;
            *(float4*)(ts + rr * 68 + c4) = *(const float4*)(T + rr * 64 + c4);
        }
    }

    // collapse: w[row][kq*8 .. +8] from mp,mv (fp32 math, bf16 inputs)
    {
        const int row = t >> 3, kq = t & 7;
        float g[8];
#pragma unroll
        for (int i = 0; i < 8; ++i) g[i] = gw[i];
        const short8 p8 = *(const short8*)(mp + (size_t)(b0 + row) * 64 + kq * 8);
        const short8 q8 = *(const short8*)(mv + (size_t)(b0 + row) * 64 + kq * 8);
        float mpv[8], mvv[8];
#pragma unroll
        for (int i = 0; i < 8; ++i) { mpv[i] = bf2f(p8[i]); mvv[i] = bf2f(q8[i]); }

        constexpr int MSK[8] = {0, 1, 2, 4, 3, 5, 6, 7};
        float v[8];
#pragma unroll
        for (int m = 0; m < 8; ++m) {
            float s = 0.f;
#pragma unroll
            for (int j = 0; j < 8; ++j) {
                const int am = MSK[m], bm = MSK[j];
                const int par = (__popc((am >> 1) & bm) + __popc((am >> 2) & bm)) & 1;
                const float sg = par ? -1.f : 1.f;
                s = fmaf(sg * g[MSK[am ^ bm]], mvv[j], s);
            }
            v[m] = s;
        }
#pragma unroll
        for (int l2 = 0; l2 < 8; ++l2) {
            float s = 0.f;
#pragma unroll
            for (int i = 0; i < 8; ++i) {
                const int am = MSK[i], bm = MSK[l2];
                const int par = (__popc((am >> 1) & bm) + __popc((am >> 2) & bm)) & 1;
                const float sg = par ? -1.f : 1.f;
                s = fmaf(sg * mpv[i], v[MSK[am ^ bm]], s);
            }
            wfl[row * 68 + kq * 8 + l2] = s;
        }
    }
    __syncthreads();

    // readout: thread group-of-8 owns one b-row; w row in registers;
    // ts reads: 8 distinct rows x 8-fold broadcast -> conflict-free.
    {
        const int rr = t >> 3, rl = t & 7;
        float4 wv[16];
#pragma unroll
        for (int cc = 0; cc < 16; ++cc)
            wv[cc] = *(const float4*)(wfl + rr * 68 + cc * 4);
#pragma unroll
        for (int k = 0; k < 12; ++k) {
            const int r = rl + (k << 3);
            if (r < R_) {
                float s = 0.f;
#pragma unroll
                for (int cc = 0; cc < 16; ++cc) {
                    const float4 tv = *(const float4*)(ts + r * 68 + cc * 4);
                    s += wv[cc].x * tv.x + wv[cc].y * tv.y
                       + wv[cc].z * tv.z + wv[cc].w * tv.w;
                }
                out[(size_t)(b0 + rr) * R_ + r] = 0.125f * s;
            }
        }
    }
}

extern "C" void kernel_launch(void* const* d_in, const int* in_sizes, int n_in,
                              void* d_out, int out_size, void* d_ws, size_t ws_size,
                              hipStream_t stream)
{
    const float* h_p = (const float*)d_in[0];
    const float* h_v = (const float*)d_in[1];
    const float* Wp1 = (const float*)d_in[2];
    const float* bp1 = (const float*)d_in[3];
    const float* lgp = (const float*)d_in[4];
    const float* lbp = (const float*)d_in[5];
    const float* Wp2 = (const float*)d_in[6];
    const float* bp2 = (const float*)d_in[7];
    const float* Wv1 = (const float*)d_in[8];
    const float* bv1 = (const float*)d_in[9];
    const float* lgv = (const float*)d_in[10];
    const float* lbv = (const float*)d_in[11];
    const float* Wv2 = (const float*)d_in[12];
    const float* bv2 = (const float*)d_in[13];
    const float* T   = (const float*)d_in[14];
    const float* gw  = (const float*)d_in[15];
    float* out = (float*)d_out;

    // ws layout (4.78 MB), R4/R7-verbatim:
    short* W1c_p = (short*)d_ws;                 // [16][256][32]
    short* W1c_v = W1c_p + 16 * 256 * 32;
    short* W2t_p = W1c_v + 16 * 256 * 32;        // [64][256]
    short* W2t_v = W2t_p + 64 * 256;
    short* mp    = W2t_v + 64 * 256;             // (B,64) bf16
    short* mv    = mp + (size_t)B_ * 64;         // (B,64) bf16

    cdd_prep_kernel<<<512, 256, 0, stream>>>(Wp1, Wv1, Wp2, Wv2,
                                             W1c_p, W1c_v, W2t_p, W2t_v);
    dim3 g1(B_ / 64, 2);
    cdd_proj_kernel<<<g1, 256, 0, stream>>>(h_p, h_v,
                                            bp1, lgp, lbp, bp2,
                                            bv1, lgv, lbv, bv2,
                                            W1c_p, W1c_v, W2t_p, W2t_v,
                                            mp, mv);
    cdd_cliff_kernel<<<B_ / 32, 256, 0, stream>>>(mp, mv, T, gw, out);
}